// Round 8
// baseline (256.782 us; speedup 1.0000x reference)
//
#include <hip/hip_runtime.h>
#include <math.h>

#define T_TOKENS 16384
#define HDIM     2048
#define NEXP     128
#define TOPK     8

#define KSPLIT   4
#define KRANGE   (HDIM / KSPLIT)   // 512 k per wave
#define BK       64                // k per staged chunk (2 MFMA k-steps)
#define NCHW     (KRANGE / BK)     // 8 chunks per wave
#define KPAD     72                // f16 row stride in staging LDS

#define F16_MIN_NORM    6.1035156e-05f
#define SPLIT_SCALE     4096.0f
#define INV_SPLIT_SCALE 2.44140625e-04f   // 2^-12

typedef __attribute__((ext_vector_type(8))) _Float16 f16x8;  // A/B frag: 4 VGPR
typedef __attribute__((ext_vector_type(4))) float    f32x4;  // C/D frag + nontemporal loads

// x = hi + lo*2^-12 (f16 RNE each); residual <= 2^-24|x|. Numerics verified R3-R6.
__device__ __forceinline__ void f16split(float f, _Float16& hi, _Float16& lo) {
    _Float16 h = (_Float16)f;
    float back = (float)h;
    if (fabsf(f) < F16_MIN_NORM) { h = (_Float16)0.f; back = 0.f; }
    lo = (_Float16)((f - back) * SPLIT_SCALE);
    hi = h;
}

// ---- prep: split w AND repack into MFMA B-frag order (verified R5/R6) ----
// packed[s]: ((kk*8 + nt)*64 + lane) * 8 f16; kk = global 32-k step, nt = expert/16.
__global__ __launch_bounds__(256) void pack_w(const float* __restrict__ w,
                                              unsigned short* __restrict__ wp1,
                                              unsigned short* __restrict__ wp2) {
    int p = blockIdx.x * 256 + threadIdx.x;       // 0 .. 64*8*64-1
    int lane = p & 63, nt = (p >> 6) & 7, kk = p >> 9;
    int col = lane & 15, quad = lane >> 4;
    const float* src = w + (size_t)(nt * 16 + col) * HDIM + kk * 32 + quad * 8;
    unsigned short h[8], l[8];
#pragma unroll
    for (int j = 0; j < 8; ++j) {
        _Float16 hh, ll;
        f16split(src[j], hh, ll);
        union { _Float16 x; unsigned short u; } ch, cl;
        ch.x = hh; cl.x = ll;
        h[j] = ch.u; l[j] = cl.u;
    }
    *(uint4*)(wp1 + (size_t)p * 8) = *(const uint4*)h;
    *(uint4*)(wp2 + (size_t)p * 8) = *(const uint4*)l;
}

// ---- fused gate: K-split x4, m_wave=32, wave-private double-buffered staging ----
// Block = 4 waves, 32 tokens x 128 experts; wave wv owns K-quarter [wv*512,+512),
// 2 m-tiles x 8 n-tiles. Grid = T/32 = 512 -> 2 blocks/CU. launch_bounds(256,2):
// wide VGPR budget so the full per-ks B set (16 frags) stays in flight (MLP >> R6's 2-3).
__global__ __launch_bounds__(256, 2) void moe_gate(const float* __restrict__ x,
                                                   const unsigned short* __restrict__ wp1,
                                                   const unsigned short* __restrict__ wp2,
                                                   float* __restrict__ out_idx,
                                                   float* __restrict__ out_w) {
    // staging: 4 waves x 2 buffers x 2 planes x [32][KPAD] f16 (4608 B/plane) = 73728 B
    // epilogue union: [KSPLIT][32][132] f32 = 67584 B
    __shared__ __align__(16) unsigned char smem[73728];
    float* epil = (float*)smem;

    const int tid  = threadIdx.x;
    const int lane = tid & 63;
    const int wv   = tid >> 6;
    const int col  = lane & 15;       // A: m, B: n, D: col
    const int quad = lane >> 4;       // A/B: k-seg, D: row group
    const long tok0 = (long)blockIdx.x * 32;
    const int kbase = wv * KRANGE;

    unsigned short* bufs[2][2];       // [buf][plane]
    bufs[0][0] = (unsigned short*)(smem + wv * 18432);
    bufs[0][1] = (unsigned short*)(smem + wv * 18432 + 4608);
    bufs[1][0] = (unsigned short*)(smem + wv * 18432 + 9216);
    bufs[1][1] = (unsigned short*)(smem + wv * 18432 + 13824);

    // staging map (it = 0..7): row = it*4 + (lane>>4), seg = lane&15 -> 4 f32 at seg*4.
    // Per it, 64 lanes cover 4 rows x 256 B contiguous each -> coalesced dwordx4.
    const int srow = lane >> 4, sseg = lane & 15;
    const float* xg = x + (tok0 + srow) * HDIM + kbase + sseg * 4;

    f32x4 acc[2][8], accc[2][8];      // [mt][nt] main + cross
#pragma unroll
    for (int m = 0; m < 2; ++m)
#pragma unroll
        for (int n = 0; n < 8; ++n) { acc[m][n] = (f32x4){0,0,0,0}; accc[m][n] = (f32x4){0,0,0,0}; }

    f32x4 xv[8];                       // prefetched x chunk (32 f32/lane)

    auto load_x = [&](int ch) {
#pragma unroll
        for (int it = 0; it < 8; ++it)
            xv[it] = __builtin_nontemporal_load(
                (const f32x4*)(xg + (size_t)(it * 4) * HDIM + ch * BK));
    };

    auto cvt_store = [&](int buf) {
#pragma unroll
        for (int it = 0; it < 8; ++it) {
            unsigned short h[4], l[4];
#pragma unroll
            for (int j = 0; j < 4; ++j) {
                _Float16 hh, ll;
                f16split(xv[it][j], hh, ll);
                union { _Float16 x; unsigned short u; } ch_, cl_;
                ch_.x = hh; cl_.x = ll;
                h[j] = ch_.u; l[j] = cl_.u;
            }
            const int off = (it * 4 + srow) * KPAD + sseg * 4;
            *(uint2*)(bufs[buf][0] + off) = *(const uint2*)h;
            *(uint2*)(bufs[buf][1] + off) = *(const uint2*)l;
        }
    };

    load_x(0);
    cvt_store(0);
    __builtin_amdgcn_wave_barrier();

    for (int ch = 0; ch < NCHW; ++ch) {
        const int cur = ch & 1;
        if (ch + 1 < NCHW) load_x(ch + 1);     // issue next x loads under this chunk's MFMAs

#pragma unroll
        for (int ks = 0; ks < 2; ++ks) {
            const int kk = wv * 16 + ch * 2 + ks;      // global 32-k step for packed B
            // B set for this ks: 16 independent 1 KB loads -> deep MLP
            f16x8 b1[8], b2[8];
#pragma unroll
            for (int nt = 0; nt < 8; ++nt) {
                const size_t off = ((size_t)(kk * 8 + nt) * 64 + lane) * 8;
                b1[nt] = *(const f16x8*)(wp1 + off);
                b2[nt] = *(const f16x8*)(wp2 + off);
            }
            f16x8 a1[2], a2[2];
#pragma unroll
            for (int m = 0; m < 2; ++m) {
                const int ao = (m * 16 + col) * KPAD + ks * 32 + quad * 8;
                a1[m] = *(const f16x8*)(bufs[cur][0] + ao);
                a2[m] = *(const f16x8*)(bufs[cur][1] + ao);
            }
#pragma unroll
            for (int nt = 0; nt < 8; ++nt)
#pragma unroll
                for (int m = 0; m < 2; ++m) {
                    acc[m][nt]  = __builtin_amdgcn_mfma_f32_16x16x32_f16(a1[m], b1[nt], acc[m][nt],  0, 0, 0);
                    accc[m][nt] = __builtin_amdgcn_mfma_f32_16x16x32_f16(a1[m], b2[nt], accc[m][nt], 0, 0, 0);
                    accc[m][nt] = __builtin_amdgcn_mfma_f32_16x16x32_f16(a2[m], b1[nt], accc[m][nt], 0, 0, 0);
                }
        }

        if (ch + 1 < NCHW) cvt_store(cur ^ 1); // stage next chunk into the other buffer
        __builtin_amdgcn_wave_barrier();
    }

    __syncthreads();   // staging slices about to be overwritten by epilogue partials

    // ---- epilogue: partials -> LDS; D layout: token = mt*16+quad*4+r, expert = nt*16+col ----
#pragma unroll
    for (int m = 0; m < 2; ++m)
#pragma unroll
        for (int nt = 0; nt < 8; ++nt)
#pragma unroll
            for (int r = 0; r < 4; ++r)
                epil[((size_t)wv * 32 + m * 16 + quad * 4 + r) * 132 + nt * 16 + col] =
                    acc[m][nt][r] + accc[m][nt][r] * INV_SPLIT_SCALE;
    __syncthreads();

    // ---- reduce K-quarters + top-8 + renorm softmax: 8 tokens per wave (verified R1-R6) ----
    for (int i = 0; i < 8; ++i) {
        const int t = wv * 8 + i;
        float v0 = 0.f, v1 = 0.f;
#pragma unroll
        for (int q = 0; q < KSPLIT; ++q) {
            float2 p = *(const float2*)(epil + ((size_t)q * 32 + t) * 132 + 2 * lane);
            v0 += p.x; v1 += p.y;
        }
        const int i0 = 2 * lane, i1 = 2 * lane + 1;

        float topv[TOPK];
        int topi[TOPK];
#pragma unroll
        for (int s = 0; s < TOPK; ++s) {
            float mv = (v0 >= v1) ? v0 : v1;          // tie -> smaller index
            int   mi = (v0 >= v1) ? i0 : i1;
#pragma unroll
            for (int off = 32; off >= 1; off >>= 1) { // butterfly argmax
                float ov = __shfl_xor(mv, off);
                int   oi = __shfl_xor(mi, off);
                if (ov > mv || (ov == mv && oi < mi)) { mv = ov; mi = oi; }
            }
            topv[s] = mv; topi[s] = mi;
            if (i0 == mi) v0 = -INFINITY;
            if (i1 == mi) v1 = -INFINITY;
        }

        const float m = topv[0];
        float sum = 0.f;
#pragma unroll
        for (int s = 0; s < TOPK; ++s) sum += expf(topv[s] - m);
        const float inv = 1.f / sum;

        float myv = topv[0]; int myi = topi[0];
#pragma unroll
        for (int s = 1; s < TOPK; ++s)
            if (lane == s) { myv = topv[s]; myi = topi[s]; }

        if (lane < TOPK) {
            long tok = tok0 + t;
            out_idx[tok * TOPK + lane] = (float)myi;
            out_w[tok * TOPK + lane]   = expf(myv - m) * inv;
        }
    }
}

extern "C" void kernel_launch(void* const* d_in, const int* in_sizes, int n_in,
                              void* d_out, int out_size, void* d_ws, size_t ws_size,
                              hipStream_t stream) {
    const float* x = (const float*)d_in[0];   // [4,4096,2048] fp32
    const float* w = (const float*)d_in[1];   // [128,2048] fp32
    float* out = (float*)d_out;               // [T*8 idx][T*8 weights] flat fp32

    unsigned short* wp1 = (unsigned short*)d_ws;           // 512 KB packed hi
    unsigned short* wp2 = wp1 + (size_t)NEXP * HDIM;       // 512 KB packed lo

    pack_w<<<(64 * 8 * 64) / 256, 256, 0, stream>>>(w, wp1, wp2);
    moe_gate<<<T_TOKENS / 32, 256, 0, stream>>>(x, wp1, wp2, out, out + (size_t)T_TOKENS * TOPK);
}

// Round 9
// 250.530 us; speedup vs baseline: 1.0250x; 1.0250x over previous
//
#include <hip/hip_runtime.h>
#include <math.h>

#define T_TOKENS 16384
#define HDIM     2048
#define NEXP     128
#define TOPK     8

#define BK    64                 // k per chunk (2 MFMA k-steps)
#define NCH   (HDIM / BK)        // 32 chunks

#define F16_MIN_NORM    6.1035156e-05f
#define SPLIT_SCALE     4096.0f
#define INV_SPLIT_SCALE 2.44140625e-04f   // 2^-12

typedef __attribute__((ext_vector_type(8))) _Float16 f16x8;  // A/B frag: 4 VGPR
typedef __attribute__((ext_vector_type(4))) float    f32x4;  // C/D frag + loads

// x = hi + lo*2^-12 (f16 RNE each); residual <= 2^-24|x|. Numerics verified R3-R8.
__device__ __forceinline__ void f16split(float f, _Float16& hi, _Float16& lo) {
    _Float16 h = (_Float16)f;
    float back = (float)h;
    if (fabsf(f) < F16_MIN_NORM) { h = (_Float16)0.f; back = 0.f; }
    lo = (_Float16)((f - back) * SPLIT_SCALE);
    hi = h;
}

// ---- prep: split w AND repack into MFMA B-frag order (verified R5-R8) ----
// packed[s]: ((kk*8 + nt)*64 + lane) * 8 f16; kk = global 32-k step, nt = expert/16.
__global__ __launch_bounds__(256) void pack_w(const float* __restrict__ w,
                                              unsigned short* __restrict__ wp1,
                                              unsigned short* __restrict__ wp2) {
    int p = blockIdx.x * 256 + threadIdx.x;       // 0 .. 64*8*64-1
    int lane = p & 63, nt = (p >> 6) & 7, kk = p >> 9;
    int col = lane & 15, quad = lane >> 4;
    const float* src = w + (size_t)(nt * 16 + col) * HDIM + kk * 32 + quad * 8;
    unsigned short h[8], l[8];
#pragma unroll
    for (int j = 0; j < 8; ++j) {
        _Float16 hh, ll;
        f16split(src[j], hh, ll);
        union { _Float16 x; unsigned short u; } ch, cl;
        ch.x = hh; cl.x = ll;
        h[j] = ch.u; l[j] = cl.u;
    }
    *(uint4*)(wp1 + (size_t)p * 8) = *(const uint4*)h;
    *(uint4*)(wp2 + (size_t)p * 8) = *(const uint4*)l;
}

// ---- fused gate, m97 structure: LDS-shared A+B, frag-order LDS, DMA for B ----
// Block = 256 thr = 4 waves; tile 32 tokens x 128 experts; wave wv owns experts
// [wv*32, +32) (n-tiles 2wv, 2wv+1) x 2 m-tiles over full K. Grid 512 -> 2 blocks/CU.
__global__ __launch_bounds__(256, 2) void moe_gate(const float* __restrict__ x,
                                                   const unsigned short* __restrict__ wp1,
                                                   const unsigned short* __restrict__ wp2,
                                                   float* __restrict__ out_idx,
                                                   float* __restrict__ out_w) {
    // a1/a2: A-frag planes [2kk][2m][64 lane][8 f16] = 4 KB each
    // b1/b2: B-frag planes [2kk][8nt][64 lane][8 f16] = 16 KB each  -> total 40 KB
    __shared__ __align__(16) unsigned char smem[40960];
    unsigned short* a1 = (unsigned short*)smem;
    unsigned short* a2 = (unsigned short*)(smem + 4096);
    unsigned short* b1 = (unsigned short*)(smem + 8192);
    unsigned short* b2 = (unsigned short*)(smem + 24576);
    float* epil = (float*)smem;                    // epilogue union [32][132] f32 = 16.9 KB

    const int tid  = threadIdx.x;
    const int lane = tid & 63;
    const int wv   = tid >> 6;
    const int col  = lane & 15;       // A: m, B: n, D: col
    const int quad = lane >> 4;       // A/B: k-seg, D: row group
    const long tok0 = (long)blockIdx.x * 32;

    // A staging: thread t -> row = t>>3 (0..31), kseg = t&7 -> 8 f32 at k = kseg*8.
    // Loads coalesced (8 threads cover one 256 B row-chunk). All 8 elems share one
    // (kk_l, quad_s) -> single uint4 store per plane in frag order.
    const int srow = tid >> 3, skseg = tid & 7;
    const float* xg = x + (tok0 + srow) * HDIM + skseg * 8;
    const int kk_l = skseg >> 2, quad_s = skseg & 3;
    const int adst = (((kk_l * 2 + (srow >> 4)) * 64) + quad_s * 16 + (srow & 15)) * 8;

    f32x4 acc[2][2], accc[2][2];      // [m][n] main + cross
#pragma unroll
    for (int m = 0; m < 2; ++m)
#pragma unroll
        for (int n = 0; n < 2; ++n) { acc[m][n] = (f32x4){0,0,0,0}; accc[m][n] = (f32x4){0,0,0,0}; }

    f32x4 xv0, xv1;                    // prefetched 8 f32

    auto load_x = [&](int ch) {
        xv0 = *(const f32x4*)(xg + ch * BK);       // note: row k-offset is skseg*8 within chunk
        xv1 = *(const f32x4*)(xg + ch * BK + 4);
    };

    auto cvt_store = [&]() {
        unsigned short h[8], l[8];
#pragma unroll
        for (int j = 0; j < 8; ++j) {
            _Float16 hh, ll;
            f16split(j < 4 ? xv0[j] : xv1[j - 4], hh, ll);
            union { _Float16 x; unsigned short u; } ch_, cl_;
            ch_.x = hh; cl_.x = ll;
            h[j] = ch_.u; l[j] = cl_.u;
        }
        *(uint4*)(a1 + adst) = *(const uint4*)h;
        *(uint4*)(a2 + adst) = *(const uint4*)l;
    };

    load_x(0);
    for (int ch = 0; ch < NCH; ++ch) {
        cvt_store();                               // A f32->f16 planes, frag order
        // B DMA: 16 KB per plane per chunk, frag-packed source is linear -> lane-contiguous
        {
            const unsigned short* s1 = wp1 + (size_t)ch * 8192;
            const unsigned short* s2 = wp2 + (size_t)ch * 8192;
#pragma unroll
            for (int i = 0; i < 4; ++i) {
                const int off = (i * 256 + tid) * 8;     // f16 units, 16 B per thread
                __builtin_amdgcn_global_load_lds((const __attribute__((address_space(1))) void*)(s1 + off),
                                                 (__attribute__((address_space(3))) void*)(b1 + off), 16, 0, 0);
                __builtin_amdgcn_global_load_lds((const __attribute__((address_space(1))) void*)(s2 + off),
                                                 (__attribute__((address_space(3))) void*)(b2 + off), 16, 0, 0);
            }
        }
        __syncthreads();                           // A stores visible + DMA drained
        if (ch + 1 < NCH) load_x(ch + 1);          // prefetch next chunk's x under compute

#pragma unroll
        for (int kk = 0; kk < 2; ++kk) {
            f16x8 af1[2], af2[2];
#pragma unroll
            for (int m = 0; m < 2; ++m) {          // contiguous b128, conflict-free
                const int ao = ((kk * 2 + m) * 64 + lane) * 8;
                af1[m] = *(const f16x8*)(a1 + ao);
                af2[m] = *(const f16x8*)(a2 + ao);
            }
#pragma unroll
            for (int n = 0; n < 2; ++n) {
                const int nt = 2 * wv + n;
                const int bo = ((kk * 8 + nt) * 64 + lane) * 8;
                f16x8 bf1 = *(const f16x8*)(b1 + bo);
                f16x8 bf2 = *(const f16x8*)(b2 + bo);
#pragma unroll
                for (int m = 0; m < 2; ++m) {
                    acc[m][n]  = __builtin_amdgcn_mfma_f32_16x16x32_f16(af1[m], bf1, acc[m][n],  0, 0, 0);
                    accc[m][n] = __builtin_amdgcn_mfma_f32_16x16x32_f16(af1[m], bf2, accc[m][n], 0, 0, 0);
                    accc[m][n] = __builtin_amdgcn_mfma_f32_16x16x32_f16(af2[m], bf1, accc[m][n], 0, 0, 0);
                }
            }
        }
        __syncthreads();                           // all frag reads done before next stores
    }

    // ---- epilogue: logits -> LDS; D layout: token = m*16+quad*4+r, expert = (2wv+n)*16+col
#pragma unroll
    for (int m = 0; m < 2; ++m)
#pragma unroll
        for (int n = 0; n < 2; ++n)
#pragma unroll
            for (int r = 0; r < 4; ++r)
                epil[(m * 16 + quad * 4 + r) * 132 + (2 * wv + n) * 16 + col] =
                    acc[m][n][r] + accc[m][n][r] * INV_SPLIT_SCALE;
    __syncthreads();

    // ---- top-8 + renorm softmax: 8 tokens per wave (butterfly verified R1-R8) ----
    for (int i = 0; i < 8; ++i) {
        const int t = wv * 8 + i;
        float2 p = *(const float2*)(epil + t * 132 + 2 * lane);
        float v0 = p.x, v1 = p.y;
        const int i0 = 2 * lane, i1 = 2 * lane + 1;

        float topv[TOPK];
        int topi[TOPK];
#pragma unroll
        for (int s = 0; s < TOPK; ++s) {
            float mv = (v0 >= v1) ? v0 : v1;          // tie -> smaller index
            int   mi = (v0 >= v1) ? i0 : i1;
#pragma unroll
            for (int off = 32; off >= 1; off >>= 1) {
                float ov = __shfl_xor(mv, off);
                int   oi = __shfl_xor(mi, off);
                if (ov > mv || (ov == mv && oi < mi)) { mv = ov; mi = oi; }
            }
            topv[s] = mv; topi[s] = mi;
            if (i0 == mi) v0 = -INFINITY;
            if (i1 == mi) v1 = -INFINITY;
        }

        const float m = topv[0];
        float sum = 0.f;
#pragma unroll
        for (int s = 0; s < TOPK; ++s) sum += expf(topv[s] - m);
        const float inv = 1.f / sum;

        float myv = topv[0]; int myi = topi[0];
#pragma unroll
        for (int s = 1; s < TOPK; ++s)
            if (lane == s) { myv = topv[s]; myi = topi[s]; }

        if (lane < TOPK) {
            long tok = tok0 + t;
            out_idx[tok * TOPK + lane] = (float)myi;
            out_w[tok * TOPK + lane]   = expf(myv - m) * inv;
        }
    }
}

extern "C" void kernel_launch(void* const* d_in, const int* in_sizes, int n_in,
                              void* d_out, int out_size, void* d_ws, size_t ws_size,
                              hipStream_t stream) {
    const float* x = (const float*)d_in[0];   // [4,4096,2048] fp32
    const float* w = (const float*)d_in[1];   // [128,2048] fp32
    float* out = (float*)d_out;               // [T*8 idx][T*8 weights] flat fp32

    unsigned short* wp1 = (unsigned short*)d_ws;           // 512 KB packed hi
    unsigned short* wp2 = wp1 + (size_t)NEXP * HDIM;       // 512 KB packed lo

    pack_w<<<(64 * 8 * 64) / 256, 256, 0, stream>>>(w, wp1, wp2);
    moe_gate<<<T_TOKENS / 32, 256, 0, stream>>>(x, wp1, wp2, out, out + (size_t)T_TOKENS * TOPK);
}